// Round 2
// baseline (345.333 us; speedup 1.0000x reference)
//
#include <hip/hip_runtime.h>

#define NCH 128

// K1: deg[i] = 1.0 (self-loop)
__global__ void k_init_deg(float* deg, int n) {
    int i = blockIdx.x * blockDim.x + threadIdx.x;
    if (i < n) deg[i] = 1.0f;
}

// K2: deg[col[e]] += 1 for each edge
__global__ void k_count_deg(const int* __restrict__ col, int e, float* deg) {
    int i = blockIdx.x * blockDim.x + threadIdx.x;
    if (i < e) atomicAdd(&deg[col[i]], 1.0f);
}

// K3: dis[i] = rsqrt(deg[i])   (deg >= 1 always, no guard needed)
__global__ void k_rsqrt(float* deg, int n) {
    int i = blockIdx.x * blockDim.x + threadIdx.x;
    if (i < n) deg[i] = rsqrtf(deg[i]);
}

// K4: out[i][c] = dis[i]^2 * (x[i]·W[:,c]) + b[c]   -- full overwrite of d_out
__global__ void k_self(const float* __restrict__ x, const float* __restrict__ W,
                       const float* __restrict__ b, const float* __restrict__ dis,
                       float* __restrict__ out, int n) {
    long long t = (long long)blockIdx.x * blockDim.x + threadIdx.x;
    if (t >= (long long)n * NCH) return;
    int i = (int)(t >> 7);
    int c = (int)(t & (NCH - 1));
    float x0 = x[i * 4 + 0], x1 = x[i * 4 + 1], x2 = x[i * 4 + 2], x3 = x[i * 4 + 3];
    float xw = x0 * W[0 * NCH + c] + x1 * W[1 * NCH + c]
             + x2 * W[2 * NCH + c] + x3 * W[3 * NCH + c];
    float d = dis[i];
    out[t] = d * d * xw + b[c];
}

// K5: out[col[e]][c] += dis[row]*dis[col] * (x[row]·W[:,c])
__global__ void k_scatter(const float* __restrict__ x,
                          const int* __restrict__ row,
                          const int* __restrict__ col,
                          const float* __restrict__ W,
                          const float* __restrict__ dis,
                          float* __restrict__ out, int e) {
    long long t = (long long)blockIdx.x * blockDim.x + threadIdx.x;
    if (t >= (long long)e * NCH) return;
    int ei = (int)(t >> 7);
    int c  = (int)(t & (NCH - 1));
    int r  = row[ei];
    int cl = col[ei];
    float x0 = x[r * 4 + 0], x1 = x[r * 4 + 1], x2 = x[r * 4 + 2], x3 = x[r * 4 + 3];
    float xw = x0 * W[0 * NCH + c] + x1 * W[1 * NCH + c]
             + x2 * W[2 * NCH + c] + x3 * W[3 * NCH + c];
    float nrm = dis[r] * dis[cl];
    atomicAdd(&out[(long long)cl * NCH + c], xw * nrm);
}

extern "C" void kernel_launch(void* const* d_in, const int* in_sizes, int n_in,
                              void* d_out, int out_size, void* d_ws, size_t ws_size,
                              hipStream_t stream) {
    const float* x  = (const float*)d_in[0];
    const int*   ei = (const int*)d_in[1];     // int64 in ref -> pushed as int32
    const float* W  = (const float*)d_in[2];
    const float* b  = (const float*)d_in[3];
    float* out = (float*)d_out;

    int n = in_sizes[0] / 4;       // 100000
    int E = in_sizes[1] / 2;       // 640000
    const int* row = ei;           // edge_index[0] = sources
    const int* col = ei + E;       // edge_index[1] = targets

    float* dis = (float*)d_ws;     // n floats

    const int B = 256;
    k_init_deg<<<(n + B - 1) / B, B, 0, stream>>>(dis, n);
    k_count_deg<<<(E + B - 1) / B, B, 0, stream>>>(col, E, dis);
    k_rsqrt<<<(n + B - 1) / B, B, 0, stream>>>(dis, n);

    long long selfT = (long long)n * NCH;
    k_self<<<(int)((selfT + B - 1) / B), B, 0, stream>>>(x, W, b, dis, out, n);

    long long scatT = (long long)E * NCH;
    k_scatter<<<(int)((scatT + B - 1) / B), B, 0, stream>>>(x, row, col, W, dis, out, E);
}

// Round 3
// 199.043 us; speedup vs baseline: 1.7350x; 1.7350x over previous
//
#include <hip/hip_runtime.h>

#define NCH 128
#define SB  1024   // scan block width (bins per block)

// ---- phase 1: degree histogram ------------------------------------------
__global__ void k_zero(int* cnt, int n) {
    int i = blockIdx.x * blockDim.x + threadIdx.x;
    if (i < n) cnt[i] = 0;
}

__global__ void k_hist(const int* __restrict__ col, int e, int* cnt) {
    int i = blockIdx.x * blockDim.x + threadIdx.x;
    if (i < e) atomicAdd(&cnt[col[i]], 1);
}

// dis[i] = rsqrt(1 + indeg)  (the +1 is the self-loop)
__global__ void k_dis(const int* __restrict__ cnt, float* __restrict__ dis, int n) {
    int i = blockIdx.x * blockDim.x + threadIdx.x;
    if (i < n) dis[i] = rsqrtf(1.0f + (float)cnt[i]);
}

// ---- phase 2: exclusive scan of cnt -> offsets ---------------------------
__global__ void k_scanA(const int* __restrict__ cnt, int* __restrict__ offs,
                        int* __restrict__ bsums, int n) {
    __shared__ int s[SB];
    int tid = threadIdx.x;
    int gid = blockIdx.x * SB + tid;
    int v = (gid < n) ? cnt[gid] : 0;
    s[tid] = v;
    __syncthreads();
    for (int off = 1; off < SB; off <<= 1) {
        int t = (tid >= off) ? s[tid - off] : 0;
        __syncthreads();
        s[tid] += t;
        __syncthreads();
    }
    if (gid < n) offs[gid] = s[tid] - v;       // exclusive within block
    if (tid == SB - 1) bsums[blockIdx.x] = s[tid];
}

__global__ void k_scanB(int* bsums, int nb) {   // single block, nb <= 128
    __shared__ int s[128];
    int tid = threadIdx.x;
    int v = (tid < nb) ? bsums[tid] : 0;
    s[tid] = v;
    __syncthreads();
    for (int off = 1; off < 128; off <<= 1) {
        int t = (tid >= off) ? s[tid - off] : 0;
        __syncthreads();
        s[tid] += t;
        __syncthreads();
    }
    if (tid < nb) bsums[tid] = s[tid] - v;      // exclusive block prefix
}

__global__ void k_scanC(int* __restrict__ offs, const int* __restrict__ bsums,
                        int* __restrict__ cursor, int n, int e) {
    int i = blockIdx.x * blockDim.x + threadIdx.x;
    if (i < n) {
        int o = offs[i] + bsums[i / SB];
        offs[i] = o;
        cursor[i] = o;
    }
    if (i == 0) offs[n] = e;
}

// ---- phase 3: counting-sort fill (CSR edge list) -------------------------
__global__ void k_fill(const int* __restrict__ row, const int* __restrict__ col,
                       int* __restrict__ cursor, int* __restrict__ srow, int e) {
    int i = blockIdx.x * blockDim.x + threadIdx.x;
    if (i < e) {
        int slot = atomicAdd(&cursor[col[i]], 1);
        srow[slot] = row[i];
    }
}

// ---- phase 4: gather-aggregate, one store per output element -------------
// out[i][c] = dis[i] * ( sum_{r in nbrs(i)} dis[r]*xw(r,c) + dis[i]*xw(i,c) ) + b[c]
__global__ void k_gather(const float* __restrict__ x, const float* __restrict__ W,
                         const float* __restrict__ b, const float* __restrict__ dis,
                         const int* __restrict__ offs, const int* __restrict__ srow,
                         float* __restrict__ out, int n) {
    long long t = (long long)blockIdx.x * blockDim.x + threadIdx.x;
    if (t >= (long long)n * NCH) return;
    int i = (int)(t >> 7);
    int c = (int)(t & (NCH - 1));

    float w0 = W[0 * NCH + c], w1 = W[1 * NCH + c];
    float w2 = W[2 * NCH + c], w3 = W[3 * NCH + c];

    float di = dis[i];
    float acc = di * (x[i * 4 + 0] * w0 + x[i * 4 + 1] * w1 +
                      x[i * 4 + 2] * w2 + x[i * 4 + 3] * w3);  // self term (pre-scaled by di)

    int j0 = offs[i], j1 = offs[i + 1];
    for (int j = j0; j < j1; ++j) {
        int r = srow[j];
        float xw = x[r * 4 + 0] * w0 + x[r * 4 + 1] * w1 +
                   x[r * 4 + 2] * w2 + x[r * 4 + 3] * w3;
        acc += dis[r] * xw;
    }
    out[t] = di * acc + b[c];
}

extern "C" void kernel_launch(void* const* d_in, const int* in_sizes, int n_in,
                              void* d_out, int out_size, void* d_ws, size_t ws_size,
                              hipStream_t stream) {
    const float* x  = (const float*)d_in[0];
    const int*   ei = (const int*)d_in[1];     // int64 in ref -> pushed as int32
    const float* W  = (const float*)d_in[2];
    const float* b  = (const float*)d_in[3];
    float* out = (float*)d_out;

    int n = in_sizes[0] / 4;       // 100000
    int E = in_sizes[1] / 2;       // 640000
    const int* row = ei;           // sources
    const int* col = ei + E;       // targets

    // workspace layout (all 4-byte elems): dis | cnt(->cursor) | offs(n+1) | bsums(128) | srow(E)
    float* dis   = (float*)d_ws;
    int*   cnt   = (int*)d_ws + n;           // reused as cursor after scan
    int*   offs  = (int*)d_ws + 2 * n;
    int*   bsums = (int*)d_ws + 3 * n + 1;
    int*   srow  = (int*)d_ws + 3 * n + 1 + 128;

    const int B = 256;
    int nb = (n + SB - 1) / SB;    // scan blocks (98)

    k_zero<<<(n + B - 1) / B, B, 0, stream>>>(cnt, n);
    k_hist<<<(E + B - 1) / B, B, 0, stream>>>(col, E, cnt);
    k_dis <<<(n + B - 1) / B, B, 0, stream>>>(cnt, dis, n);

    k_scanA<<<nb, SB, 0, stream>>>(cnt, offs, bsums, n);
    k_scanB<<<1, 128, 0, stream>>>(bsums, nb);
    k_scanC<<<(n + B - 1) / B, B, 0, stream>>>(offs, bsums, cnt /*cursor*/, n, E);

    k_fill<<<(E + B - 1) / B, B, 0, stream>>>(row, col, cnt /*cursor*/, srow, E);

    long long gT = (long long)n * NCH;
    k_gather<<<(int)((gT + B - 1) / B), B, 0, stream>>>(x, W, b, dis, offs, srow, out, n);
}

// Round 4
// 185.893 us; speedup vs baseline: 1.8577x; 1.0707x over previous
//
#include <hip/hip_runtime.h>

#define NCH 128

// ws layout: agg[N][4] (float4-aligned, first) | cnt[N]
// K1: zero cnt and agg
__global__ void k_init(int* __restrict__ cnt, float4* __restrict__ agg, int n) {
    int i = blockIdx.x * blockDim.x + threadIdx.x;
    if (i < n) {
        cnt[i] = 0;
        agg[i] = make_float4(0.f, 0.f, 0.f, 0.f);
    }
}

// K2: in-degree histogram over targets
__global__ void k_hist(const int* __restrict__ col, int e, int* __restrict__ cnt) {
    int i = blockIdx.x * blockDim.x + threadIdx.x;
    if (i < e) atomicAdd(&cnt[col[i]], 1);
}

// K3: agg[col] += rsqrt(1+deg[row]) * x[row]   (4-dim input space!)
__global__ void k_scatter4(const float* __restrict__ x,
                           const int* __restrict__ row, const int* __restrict__ col,
                           const int* __restrict__ cnt, float* __restrict__ agg, int e) {
    int i = blockIdx.x * blockDim.x + threadIdx.x;
    if (i >= e) return;
    int r = row[i], c = col[i];
    float s = rsqrtf(1.0f + (float)cnt[r]);
    float4 xr = ((const float4*)x)[r];
    atomicAdd(&agg[c * 4 + 0], s * xr.x);
    atomicAdd(&agg[c * 4 + 1], s * xr.y);
    atomicAdd(&agg[c * 4 + 2], s * xr.z);
    atomicAdd(&agg[c * 4 + 3], s * xr.w);
}

// K4: out[i][c] = di * ((agg_i + di*x_i) · W[:,c]) + b[c], 4 channels/thread
__global__ void k_out(const float* __restrict__ x, const float* __restrict__ W,
                      const float* __restrict__ b, const int* __restrict__ cnt,
                      const float* __restrict__ agg, float* __restrict__ out, int n) {
    int t = blockIdx.x * blockDim.x + threadIdx.x;   // t = node*32 + c4grp
    if (t >= n * 32) return;
    int i  = t >> 5;
    int c4 = (t & 31) * 4;

    float di = rsqrtf(1.0f + (float)cnt[i]);
    float4 ai = ((const float4*)agg)[i];
    float4 xi = ((const float4*)x)[i];
    float m0 = ai.x + di * xi.x, m1 = ai.y + di * xi.y;
    float m2 = ai.z + di * xi.z, m3 = ai.w + di * xi.w;

    float4 w0 = *(const float4*)&W[0 * NCH + c4];
    float4 w1 = *(const float4*)&W[1 * NCH + c4];
    float4 w2 = *(const float4*)&W[2 * NCH + c4];
    float4 w3 = *(const float4*)&W[3 * NCH + c4];
    float4 bb = *(const float4*)&b[c4];

    float4 o;
    o.x = di * (m0 * w0.x + m1 * w1.x + m2 * w2.x + m3 * w3.x) + bb.x;
    o.y = di * (m0 * w0.y + m1 * w1.y + m2 * w2.y + m3 * w3.y) + bb.y;
    o.z = di * (m0 * w0.z + m1 * w1.z + m2 * w2.z + m3 * w3.z) + bb.z;
    o.w = di * (m0 * w0.w + m1 * w1.w + m2 * w2.w + m3 * w3.w) + bb.w;
    ((float4*)out)[t] = o;
}

extern "C" void kernel_launch(void* const* d_in, const int* in_sizes, int n_in,
                              void* d_out, int out_size, void* d_ws, size_t ws_size,
                              hipStream_t stream) {
    const float* x  = (const float*)d_in[0];
    const int*   ei = (const int*)d_in[1];     // int64 in ref -> pushed as int32
    const float* W  = (const float*)d_in[2];
    const float* b  = (const float*)d_in[3];
    float* out = (float*)d_out;

    int n = in_sizes[0] / 4;       // 100000
    int E = in_sizes[1] / 2;       // 640000
    const int* row = ei;           // sources
    const int* col = ei + E;       // targets

    float* agg = (float*)d_ws;             // N float4 (16B aligned at ws base)
    int*   cnt = (int*)d_ws + 4 * n;       // N ints

    const int B = 256;
    k_init    <<<(n + B - 1) / B, B, 0, stream>>>(cnt, (float4*)agg, n);
    k_hist    <<<(E + B - 1) / B, B, 0, stream>>>(col, E, cnt);
    k_scatter4<<<(E + B - 1) / B, B, 0, stream>>>(x, row, col, cnt, agg, E);

    int oT = n * 32;
    k_out     <<<(oT + B - 1) / B, B, 0, stream>>>(x, W, b, cnt, agg, out, n);
}

// Round 5
// 100.836 us; speedup vs baseline: 3.4247x; 1.8435x over previous
//
#include <hip/hip_runtime.h>

#define NCH 128
#define SB  1024   // scan block width

// ---- CSR build ----------------------------------------------------------
__global__ void k_zero(int* cnt, int n) {
    int i = blockIdx.x * blockDim.x + threadIdx.x;
    if (i < n) cnt[i] = 0;
}

__global__ void k_hist(const int* __restrict__ col, int e, int* __restrict__ cnt) {
    int i = blockIdx.x * blockDim.x + threadIdx.x;
    if (i < e) atomicAdd(&cnt[col[i]], 1);
}

__global__ void k_scanA(const int* __restrict__ cnt, int* __restrict__ offs,
                        int* __restrict__ bsums, int n) {
    __shared__ int s[SB];
    int tid = threadIdx.x;
    int gid = blockIdx.x * SB + tid;
    int v = (gid < n) ? cnt[gid] : 0;
    s[tid] = v;
    __syncthreads();
    for (int off = 1; off < SB; off <<= 1) {
        int t = (tid >= off) ? s[tid - off] : 0;
        __syncthreads();
        s[tid] += t;
        __syncthreads();
    }
    if (gid < n) offs[gid] = s[tid] - v;       // exclusive within block
    if (tid == SB - 1) bsums[blockIdx.x] = s[tid];
}

__global__ void k_scanB(int* bsums, int nb) {   // single block, nb <= 128
    __shared__ int s[128];
    int tid = threadIdx.x;
    int v = (tid < nb) ? bsums[tid] : 0;
    s[tid] = v;
    __syncthreads();
    for (int off = 1; off < 128; off <<= 1) {
        int t = (tid >= off) ? s[tid - off] : 0;
        __syncthreads();
        s[tid] += t;
        __syncthreads();
    }
    if (tid < nb) bsums[tid] = s[tid] - v;      // exclusive block prefix
}

__global__ void k_scanC(int* __restrict__ offs, const int* __restrict__ bsums,
                        int* __restrict__ cursor, int n, int e) {
    int i = blockIdx.x * blockDim.x + threadIdx.x;
    if (i < n) {
        int o = offs[i] + bsums[i / SB];
        offs[i] = o;
        cursor[i] = o;
    }
    if (i == 0) offs[n] = e;
}

__global__ void k_fill(const int* __restrict__ row, const int* __restrict__ col,
                       int* __restrict__ cursor, int* __restrict__ srow, int e) {
    int i = blockIdx.x * blockDim.x + threadIdx.x;
    if (i < e) {
        int slot = atomicAdd(&cursor[col[i]], 1);
        srow[slot] = row[i];
    }
}

// ---- aggregation in 4-dim input space -----------------------------------
// sx[i] = rsqrt(1+deg_i) * x[i]  (deg from offs diff; also the self term)
__global__ void k_prep(const float4* __restrict__ x, const int* __restrict__ offs,
                       float4* __restrict__ sx, int n) {
    int i = blockIdx.x * blockDim.x + threadIdx.x;
    if (i >= n) return;
    float di = rsqrtf(1.0f + (float)(offs[i + 1] - offs[i]));
    float4 v = x[i];
    sx[i] = make_float4(di * v.x, di * v.y, di * v.z, di * v.w);
}

// m[i] = di * ( sx[i] + sum_{r in nbrs(i)} sx[r] )
__global__ void k_gather4(const float4* __restrict__ sx, const int* __restrict__ offs,
                          const int* __restrict__ srow, float4* __restrict__ m, int n) {
    int i = blockIdx.x * blockDim.x + threadIdx.x;
    if (i >= n) return;
    int j0 = offs[i], j1 = offs[i + 1];
    float4 a = sx[i];                          // self term (di*x_i)
    float ax = a.x, ay = a.y, az = a.z, aw = a.w;
    int j = j0;
    for (; j + 1 < j1; j += 2) {               // 2-way unroll for load overlap
        int r0 = srow[j], r1 = srow[j + 1];
        float4 s0 = sx[r0], s1 = sx[r1];
        ax += s0.x + s1.x; ay += s0.y + s1.y;
        az += s0.z + s1.z; aw += s0.w + s1.w;
    }
    if (j < j1) {
        float4 s0 = sx[srow[j]];
        ax += s0.x; ay += s0.y; az += s0.z; aw += s0.w;
    }
    float di = rsqrtf(1.0f + (float)(j1 - j0));
    m[i] = make_float4(di * ax, di * ay, di * az, di * aw);
}

// ---- output: out[i][c] = m_i . W[:,c] + b[c] ----------------------------
__global__ void k_out(const float4* __restrict__ m, const float* __restrict__ W,
                      const float* __restrict__ b, float* __restrict__ out, int n) {
    int t = blockIdx.x * blockDim.x + threadIdx.x;   // node*32 + c4grp
    if (t >= n * 32) return;
    int i  = t >> 5;
    int c4 = (t & 31) * 4;

    float4 mi = m[i];
    float4 w0 = *(const float4*)&W[0 * NCH + c4];
    float4 w1 = *(const float4*)&W[1 * NCH + c4];
    float4 w2 = *(const float4*)&W[2 * NCH + c4];
    float4 w3 = *(const float4*)&W[3 * NCH + c4];
    float4 bb = *(const float4*)&b[c4];

    float4 o;
    o.x = mi.x * w0.x + mi.y * w1.x + mi.z * w2.x + mi.w * w3.x + bb.x;
    o.y = mi.x * w0.y + mi.y * w1.y + mi.z * w2.y + mi.w * w3.y + bb.y;
    o.z = mi.x * w0.z + mi.y * w1.z + mi.z * w2.z + mi.w * w3.z + bb.z;
    o.w = mi.x * w0.w + mi.y * w1.w + mi.z * w2.w + mi.w * w3.w + bb.w;
    ((float4*)out)[t] = o;
}

extern "C" void kernel_launch(void* const* d_in, const int* in_sizes, int n_in,
                              void* d_out, int out_size, void* d_ws, size_t ws_size,
                              hipStream_t stream) {
    const float* x  = (const float*)d_in[0];
    const int*   ei = (const int*)d_in[1];     // int64 in ref -> pushed as int32
    const float* W  = (const float*)d_in[2];
    const float* b  = (const float*)d_in[3];
    float* out = (float*)d_out;

    int n = in_sizes[0] / 4;       // 100000
    int E = in_sizes[1] / 2;       // 640000
    const int* row = ei;           // sources
    const int* col = ei + E;       // targets

    // ws layout (4B elems): sx[4n] | m[4n] | cnt[n] | offs[n+1] | bsums[128] | srow[E]
    float* sx    = (float*)d_ws;
    float* mbuf  = (float*)d_ws + 4 * n;
    int*   cnt   = (int*)d_ws + 8 * n;          // reused as cursor
    int*   offs  = (int*)d_ws + 9 * n;
    int*   bsums = (int*)d_ws + 10 * n + 1;
    int*   srow  = (int*)d_ws + 10 * n + 1 + 128;

    const int B = 256;
    int nb = (n + SB - 1) / SB;

    k_zero <<<(n + B - 1) / B, B, 0, stream>>>(cnt, n);
    k_hist <<<(E + B - 1) / B, B, 0, stream>>>(col, E, cnt);
    k_scanA<<<nb, SB, 0, stream>>>(cnt, offs, bsums, n);
    k_scanB<<<1, 128, 0, stream>>>(bsums, nb);
    k_scanC<<<(n + B - 1) / B, B, 0, stream>>>(offs, bsums, cnt /*cursor*/, n, E);
    k_fill <<<(E + B - 1) / B, B, 0, stream>>>(row, col, cnt /*cursor*/, srow, E);

    k_prep   <<<(n + B - 1) / B, B, 0, stream>>>((const float4*)x, offs, (float4*)sx, n);
    k_gather4<<<(n + B - 1) / B, B, 0, stream>>>((const float4*)sx, offs, srow, (float4*)mbuf, n);

    int oT = n * 32;
    k_out  <<<(oT + B - 1) / B, B, 0, stream>>>((const float4*)mbuf, W, b, out, n);
}